// Round 8
// baseline (249.513 us; speedup 1.0000x reference)
//
#include <hip/hip_runtime.h>
#include <cmath>

typedef __attribute__((ext_vector_type(8))) short bf16x8;
typedef __attribute__((ext_vector_type(4))) short s16x4;
typedef __attribute__((ext_vector_type(4))) float f32x4;

#define MFMA_BF16 __builtin_amdgcn_mfma_f32_16x16x32_bf16

__device__ __forceinline__ float bf2f(short s) {
    unsigned u = ((unsigned)(unsigned short)s) << 16;
    return __builtin_bit_cast(float, u);
}
__device__ __forceinline__ short f2bf(float f) {
    unsigned u = __builtin_bit_cast(unsigned, f);
    u += 0x7fffu + ((u >> 16) & 1u);   // RNE
    return (short)(u >> 16);
}

__device__ __forceinline__ void gl_lds16(const short* gp, short* lp) {
    __builtin_amdgcn_global_load_lds(
        (const __attribute__((address_space(1))) unsigned int*)gp,
        (__attribute__((address_space(3))) unsigned int*)lp, 16, 0, 0);
}

// Fused fp32->bf16 conversion for 5 tensors; every segment size is a
// multiple of 1024 so each 256-thread block (4 elems/thread) stays in one.
// (R4: fusing this into the GEMMs tripled FETCH_SIZE; dedup pass is load-
// bearing. At BW roofline: 82MB ~ 13us.)
__global__ __launch_bounds__(256) void cvt5(
    const float* s0, short* d0, int n0,
    const float* s1, short* d1, int n1,
    const float* s2, short* d2, int n2,
    const float* s3, short* d3, int n3,
    const float* s4, short* d4, int n4)
{
    long long i = (long long)blockIdx.x * 1024 + threadIdx.x * 4;
    const float* s; short* d;
    if      (i < n0)                  { s = s0; d = d0; }
    else if ((i -= n0) < n1)          { s = s1; d = d1; }
    else if ((i -= n1) < n2)          { s = s2; d = d2; }
    else if ((i -= n2) < n3)          { s = s3; d = d3; }
    else      { i -= n3;                s = s4; d = d4; }
    float4 v = *(const float4*)(s + i);
    s16x4 o;
    o[0] = f2bf(v.x); o[1] = f2bf(v.y); o[2] = f2bf(v.z); o[3] = f2bf(v.w);
    *(s16x4*)(d + i) = o;
}

// 128x64-tile GEMM, 8-wave K-split variant. C = A @ W^T (+bias).
// R8 change (one variable vs R5): 512 threads. Wave pairs (w, w+4) split
// the two 32-K halves of each BK=64 tile -- wave w computes ONLY half
// kg = w>>2 into its own accumulator; partial accs combined once via LDS
// after the K-loop. Per-block-iter MFMA (64), ds_read_b128 (48), staged
// bytes (24KB), and barrier count are IDENTICAL to the proven R5 kernel;
// only waves/CU doubles 12->24 so barrier drains are hidden by 16 other
// runnable waves instead of 8. Pure latency-hiding test at zero pipe-cost
// delta. (Refuted levers: counted-vmcnt R1, BK=32 R3, 64x64 tile R5,
// A-direct-to-reg R6, cvt fusion R4.)
// XCD region swizzle (T1): FETCH 39->28.8 MB, -4.3us (R5).
// LDS: per 32-K half, 1KB chunks of 16 rows; XOR swizzle f(row)=(row>>1)&3:
// lane L stages (row = chunk*16 + L>>2, kq = (L&3)^f(L>>2)) at slot L;
// fragment read slot = l15*4 + (quad^f(l15)) -> conflict-free b128.
// MODE 0: QKV fused epilogue; MODE 1: fp32 out + bias (bq slot).
template <int MODE>
__global__ __launch_bounds__(512) void gemm_t(
    const short* __restrict__ A, const short* __restrict__ W,
    const float* __restrict__ bq, const float* __restrict__ bk,
    const float* __restrict__ bv,
    short* __restrict__ qo, short* __restrict__ ko, short* __restrict__ vo,
    float* __restrict__ fo,
    int M, int K, int S, int Hkv, int Nq, int Nkv, int N)
{
    __shared__ __align__(16) short As[2][2 * 8 * 512];   // 2 bufs x 16KB
    __shared__ __align__(16) short Bs[2][2 * 4 * 512];   // 2 bufs x 8KB

    const int w    = threadIdx.x >> 6;     // 0..7
    const int lane = threadIdx.x & 63;
    const int l15  = lane & 15;
    const int quad = lane >> 4;
    const int kg   = w >> 2;               // K-half this wave computes
    const int wy   = (w >> 1) & 1;
    const int wx   = w & 1;

    // XCD region swizzle (bijective): xcd = lin&7 owns a gx/4 x gy/2 patch.
    unsigned gx = gridDim.x, gy = gridDim.y;
    unsigned bx = blockIdx.x, by = blockIdx.y;
    if ((gx & 3) == 0 && (gy & 1) == 0) {
        unsigned lin = by * gx + bx;
        unsigned xcd = lin & 7, idx = lin >> 3;
        unsigned n   = gx >> 2;
        bx = (xcd & 3) * n + idx % n;
        by = (xcd >> 2) * (gy >> 1) + idx / n;
    }
    const int m0 = by * 128;
    const int n0 = bx * 64;

    const short* Ab = A + (size_t)m0 * K;
    const short* Wb = W + (size_t)n0 * K;

    const int srow = lane >> 2;                              // 0..15
    const int scol = ((lane & 3) ^ ((srow >> 1) & 3)) * 8;   // swizzled col
    // Staging split across 8 waves: wave w stages A chunks {2w, 2w+1}
    // (a = h2*8 + rowchunk) and B chunk w (beta = h2*4 + rowchunk).
    auto stage = [&](int buf, int kofs) {
#pragma unroll
        for (int i = 0; i < 2; i++) {
            const int a  = 2 * w + i;
            const int h2 = a >> 3, c = a & 7;
            gl_lds16(Ab + (size_t)(c * 16 + srow) * K + kofs + h2 * 32 + scol,
                     As[buf] + a * 512 + lane * 8);
        }
        {
            const int h2 = w >> 2, c4 = w & 3;
            gl_lds16(Wb + (size_t)(c4 * 16 + srow) * K + kofs + h2 * 32 + scol,
                     Bs[buf] + w * 512 + lane * 8);
        }
    };

    f32x4 acc[4][2];
#pragma unroll
    for (int i = 0; i < 4; i++)
#pragma unroll
        for (int j = 0; j < 2; j++) acc[i][j] = f32x4{0.f, 0.f, 0.f, 0.f};

    const int ridx = (l15 * 4 + (quad ^ ((l15 >> 1) & 3))) * 8;
    const int nk = K / 64;
    stage(0, 0);
    __syncthreads();

    for (int kt = 0; kt < nk; kt++) {
        const int cur = kt & 1;
        if (kt + 1 < nk) stage(cur ^ 1, (kt + 1) * 64);

        bf16x8 af[4], bfr[2];
#pragma unroll
        for (int i = 0; i < 4; i++)
            af[i] = *(const bf16x8*)(As[cur] + kg * 4096 + (wy * 4 + i) * 512 + ridx);
#pragma unroll
        for (int j = 0; j < 2; j++)
            bfr[j] = *(const bf16x8*)(Bs[cur] + kg * 2048 + (wx * 2 + j) * 512 + ridx);
#pragma unroll
        for (int i = 0; i < 4; i++)
#pragma unroll
            for (int j = 0; j < 2; j++)
                acc[i][j] = MFMA_BF16(af[i], bfr[j], acc[i][j], 0, 0, 0);
        __syncthreads();
    }

    // Combine K-half partials: wave w+4 hands its acc to wave w via LDS
    // (fragment layout is lane-determined, so lane L of both waves holds
    // the same (i,j,r) elements). One-time, reuses As as scratch (32KB).
    float* scratch = (float*)&As[0][0];
    if (w >= 4) {
#pragma unroll
        for (int i = 0; i < 4; i++)
#pragma unroll
            for (int j = 0; j < 2; j++)
                *(f32x4*)(scratch + (w - 4) * 2048 + (i * 2 + j) * 256 + lane * 4) = acc[i][j];
    }
    __syncthreads();
    if (w < 4) {
#pragma unroll
        for (int i = 0; i < 4; i++)
#pragma unroll
            for (int j = 0; j < 2; j++) {
                f32x4 p = *(const f32x4*)(scratch + w * 2048 + (i * 2 + j) * 256 + lane * 4);
                acc[i][j][0] += p[0]; acc[i][j][1] += p[1];
                acc[i][j][2] += p[2]; acc[i][j][3] += p[3];
            }

#pragma unroll
        for (int i = 0; i < 4; i++) {
#pragma unroll
            for (int j = 0; j < 2; j++) {
                const int col = n0 + wx * 32 + j * 16 + l15;
#pragma unroll
                for (int r = 0; r < 4; r++) {
                    const int row = m0 + wy * 64 + i * 16 + quad * 4 + r;
                    float v = acc[i][j][r];
                    if constexpr (MODE == 0) {
                        if (col < Nq) {
                            qo[(size_t)row * Nq + col] = f2bf(v + bq[col]);
                        } else if (col < Nq + Nkv) {
                            int cn = col - Nq;
                            ko[(size_t)row * Nkv + cn] = f2bf(v + bk[cn]);
                        } else {
                            int cn = col - Nq - Nkv;
                            int b  = row / S, s = row - b * S;
                            int hk = cn >> 7, dh = cn & 127;   // Dh == 128
                            vo[(size_t)((b * Hkv + hk) * 128 + dh) * S + s] = f2bf(v + bv[cn]);
                        }
                    } else {
                        fo[(size_t)row * N + col] = v + bq[col];
                    }
                }
            }
        }
    }
}

// Fused per-(token, head) LayerNorm (Dh=128) + RoPE for Q and K in one
// launch. Blocks [0, nq/4) handle Q rows, the rest K rows.
__global__ __launch_bounds__(256) void ln_rope2(
    const short* __restrict__ Xq, short* __restrict__ Yq,
    const short* __restrict__ Xk, short* __restrict__ Yk,
    const float* __restrict__ qg, const float* __restrict__ qbe,
    const float* __restrict__ kg, const float* __restrict__ kbe,
    const float* __restrict__ cosp, const float* __restrict__ sinp,
    int H, int Hkv, int S, int nq)
{
    int gw = blockIdx.x * 4 + (threadIdx.x >> 6);
    const int lane = threadIdx.x & 63;
    const short* X; short* Y; const float* g; const float* bt; int Hc;
    if (gw < nq) { X = Xq; Y = Yq; g = qg; bt = qbe; Hc = H; }
    else { gw -= nq; X = Xk; Y = Yk; g = kg; bt = kbe; Hc = Hkv; }

    const int h  = gw % Hc;
    const int rs = gw / Hc;          // b*S + s
    const int b  = rs / S;
    const int s  = rs - b * S;

    const short* x = X + ((size_t)rs * Hc + h) * 128;
    float x0 = bf2f(x[lane]), x1 = bf2f(x[lane + 64]);

    float sum = x0 + x1;
    float sq  = x0 * x0 + x1 * x1;
#pragma unroll
    for (int off = 32; off > 0; off >>= 1) {
        sum += __shfl_xor(sum, off, 64);
        sq  += __shfl_xor(sq, off, 64);
    }
    float mu  = sum * (1.f / 128.f);
    float var = sq * (1.f / 128.f) - mu * mu;
    float rinv = rsqrtf(var + 1e-5f);

    float y0 = (x0 - mu) * rinv * g[lane]      + bt[lane];
    float y1 = (x1 - mu) * rinv * g[lane + 64] + bt[lane + 64];

    float c0 = cosp[(size_t)s * 128 + lane];
    float c1 = cosp[(size_t)s * 128 + lane + 64];
    float s0 = sinp[(size_t)s * 128 + lane];
    float s1 = sinp[(size_t)s * 128 + lane + 64];

    float o0 = y0 * c0 - y1 * s0;
    float o1 = y1 * c1 + y0 * s1;

    short* yp = Y + ((size_t)(b * Hc + h) * S + s) * 128;
    yp[lane]      = f2bf(o0);
    yp[lane + 64] = f2bf(o1);
}

// Flash attention v3 (R5-proven ~39us, restored exactly: R7's setprio +
// defer-max regressed on this barrier-locked 4-wave structure).
// Q: bf16 (B,H,S,128). Kt: (B,Hkv,S,128). Vt: (B,Hkv,128,S). O: (B,S,H*128).
__global__ __launch_bounds__(256, 2) void attn(
    const short* __restrict__ Q, const short* __restrict__ Kt,
    const short* __restrict__ Vt, short* __restrict__ O,
    int S, int H, int Hkv, int nrep, float scale)
{
    __shared__ __align__(16) short Ks[2][16 * 512];
    __shared__ __align__(16) short Vs[2][16 * 512];
    __shared__ __align__(16) short P[4][16][72];

    const int w    = threadIdx.x >> 6;
    const int lane = threadIdx.x & 63;
    const int l15  = lane & 15;
    const int quad = lane >> 4;
    const int bh   = blockIdx.x;
    const int h    = bh % H;
    const int b    = bh / H;
    const int nyt  = gridDim.y;
    const int y    = blockIdx.y;
    const int qblk = (y < (nyt >> 1)) ? (nyt - 1 - y) : (y - (nyt >> 1));
    const int hk   = h / nrep;
    const int m0   = qblk * 64 + w * 16;
    const int qpos = m0 + l15;

    const short* qb = Q  + (size_t)(b * H + h) * S * 128;
    const short* kb = Kt + (size_t)(b * Hkv + hk) * S * 128;
    const short* vb = Vt + (size_t)(b * Hkv + hk) * 128 * S;

    auto stage = [&](int buf, int j0) {
#pragma unroll
        for (int i = 0; i < 8; i++) {
            if (w < 2) {
                const int s = w * 8 + i;
                const int t = s >> 2, c = s & 3;
                gl_lds16(kb + (size_t)(j0 + t * 16 + l15) * 128 + c * 32 + quad * 8,
                         Ks[buf] + s * 512 + lane * 8);
            } else {
                const int u = (w - 2) * 8 + i;
                const int c = u >> 1, hf = u & 1;
                gl_lds16(vb + (size_t)(c * 16 + l15) * S + j0 + hf * 32 + quad * 8,
                         Vs[buf] + u * 512 + lane * 8);
            }
        }
    };

    bf16x8 qf[4];
#pragma unroll
    for (int c = 0; c < 4; c++)
        qf[c] = *(const bf16x8*)(qb + (size_t)(m0 + l15) * 128 + c * 32 + quad * 8);

    f32x4 of[8];
#pragma unroll
    for (int c = 0; c < 8; c++) of[c] = f32x4{0.f, 0.f, 0.f, 0.f};
    float m_s = -1e30f, l_s = 0.f;
    const float c2 = scale * 1.44269504f;

    const int nkt = qblk + 1;
    stage(0, 0);
    __syncthreads();

    for (int kt = 0; kt < nkt; kt++) {
        const int cur = kt & 1;
        if (kt + 1 < nkt) stage(cur ^ 1, (kt + 1) * 64);

        const short* Kb = Ks[cur];
        const short* Vb = Vs[cur];
        const int j0 = kt * 64;

        f32x4 sc[4];
#pragma unroll
        for (int t = 0; t < 4; t++) sc[t] = f32x4{0.f, 0.f, 0.f, 0.f};
#pragma unroll
        for (int c = 0; c < 4; c++)
#pragma unroll
            for (int t = 0; t < 4; t++) {
                bf16x8 kf = *(const bf16x8*)(Kb + (t * 4 + c) * 512 + lane * 8);
                sc[t] = MFMA_BF16(kf, qf[c], sc[t], 0, 0, 0);
            }

        float v[4][4];
        float mx = -1e30f;
#pragma unroll
        for (int t = 0; t < 4; t++)
#pragma unroll
            for (int r = 0; r < 4; r++) {
                float s_ = sc[t][r];
                if (j0 + t * 16 + quad * 4 + r > qpos) s_ = -1e30f;
                v[t][r] = s_;
                mx = fmaxf(mx, s_);
            }
        mx = fmaxf(mx, __shfl_xor(mx, 16, 64));
        mx = fmaxf(mx, __shfl_xor(mx, 32, 64));
        float mnew  = fmaxf(m_s, mx);
        float mc    = mnew * c2;
        float alpha = exp2f(m_s * c2 - mc);
        float sum = 0.f;
        float p[4][4];
#pragma unroll
        for (int t = 0; t < 4; t++)
#pragma unroll
            for (int r = 0; r < 4; r++) {
                p[t][r] = exp2f(__builtin_fmaf(v[t][r], c2, -mc));
                sum += p[t][r];
            }
        sum += __shfl_xor(sum, 16, 64);
        sum += __shfl_xor(sum, 32, 64);
        l_s = l_s * alpha + sum;
        m_s = mnew;

#pragma unroll
        for (int c = 0; c < 8; c++) {
            f32x4 t = of[c];
            t[0] *= alpha; t[1] *= alpha; t[2] *= alpha; t[3] *= alpha;
            of[c] = t;
        }

#pragma unroll
        for (int t = 0; t < 4; t++) {
            s16x4 pk;
#pragma unroll
            for (int r = 0; r < 4; r++) pk[r] = f2bf(p[t][r]);
            *(s16x4*)(&P[w][l15][t * 16 + quad * 4]) = pk;
        }
        bf16x8 pb0 = *(const bf16x8*)(&P[w][l15][quad * 8]);
        bf16x8 pb1 = *(const bf16x8*)(&P[w][l15][32 + quad * 8]);

#pragma unroll
        for (int c = 0; c < 8; c++) {
            bf16x8 vf0 = *(const bf16x8*)(Vb + (c * 2 + 0) * 512 + lane * 8);
            bf16x8 vf1 = *(const bf16x8*)(Vb + (c * 2 + 1) * 512 + lane * 8);
            of[c] = MFMA_BF16(vf0, pb0, of[c], 0, 0, 0);
            of[c] = MFMA_BF16(vf1, pb1, of[c], 0, 0, 0);
        }
        __syncthreads();
    }

    const int HDh = H * 128;
    const float rinv = 1.0f / l_s;
    short* orow = O + ((size_t)b * S + qpos) * HDh + h * 128;
#pragma unroll
    for (int c = 0; c < 8; c++) {
        s16x4 ov;
#pragma unroll
        for (int r = 0; r < 4; r++) ov[r] = f2bf(of[c][r] * rinv);
        *(s16x4*)(orow + c * 16 + quad * 4) = ov;
    }
}

extern "C" void kernel_launch(void* const* d_in, const int* in_sizes, int n_in,
                              void* d_out, int out_size, void* d_ws, size_t ws_size,
                              hipStream_t stream) {
    const float* hs   = (const float*)d_in[0];
    const float* cosp = (const float*)d_in[1];
    const float* sinp = (const float*)d_in[2];
    const float* Wq   = (const float*)d_in[3];
    const float* bq   = (const float*)d_in[4];
    const float* Wk   = (const float*)d_in[5];
    const float* bk   = (const float*)d_in[6];
    const float* Wv   = (const float*)d_in[7];
    const float* bv   = (const float*)d_in[8];
    const float* Wo   = (const float*)d_in[9];
    const float* bo   = (const float*)d_in[10];
    const float* qg   = (const float*)d_in[11];
    const float* qb_  = (const float*)d_in[12];
    const float* kg   = (const float*)d_in[13];
    const float* kb_  = (const float*)d_in[14];

    const int Dh    = in_sizes[11];          // 128
    const int Dm    = in_sizes[10];          // 2048
    const int HDh   = in_sizes[4];           // 2048
    const int H     = HDh / Dh;              // 16
    const int HkvDh = in_sizes[6];           // 512
    const int Hkv   = HkvDh / Dh;            // 4
    const int S     = in_sizes[1] / Dh;      // 1024
    const int B     = in_sizes[0] / (S * Dm);// 2
    const int M     = B * S;                 // 2048
    const int nrep  = H / Hkv;               // 4

    // workspace layout; Wqb/Wkb/Wvb contiguous => packed (HDh+2*HkvDh, Dm)
    char* ws = (char*)d_ws;
    short* hsb  = (short*)ws;  ws += (size_t)M * Dm      * 2;  // 8 MB
    short* Wqb  = (short*)ws;  ws += (size_t)HDh * Dm    * 2;  // 8 MB
    short* Wkb  = (short*)ws;  ws += (size_t)HkvDh * Dm  * 2;  // 2 MB
    short* Wvb  = (short*)ws;  ws += (size_t)HkvDh * Dm  * 2;  // 2 MB
    short* Wob  = (short*)ws;  ws += (size_t)Dm * HDh    * 2;  // 8 MB
    short* qg16 = (short*)ws;  ws += (size_t)M * HDh     * 2;  // 8 MB
    short* kg16 = (short*)ws;  ws += (size_t)M * HkvDh   * 2;  // 2 MB
    short* qbuf = (short*)ws;  ws += (size_t)M * HDh     * 2;  // 8 MB
    short* kbuf = (short*)ws;  ws += (size_t)M * HkvDh   * 2;  // 2 MB
    short* vbuf = (short*)ws;  ws += (size_t)M * HkvDh   * 2;  // 2 MB
    short* abuf = qg16;   // alias: q-gemm output dead after ln_rope

    dim3 blk(256), blk512(512);
    const int n0 = M * Dm, n1 = HDh * Dm, n2 = HkvDh * Dm, n3 = HkvDh * Dm, n4 = Dm * HDh;
    cvt5<<<dim3((n0 + n1 + n2 + n3 + n4) / 1024), blk, 0, stream>>>(
        hs, hsb, n0, Wq, Wqb, n1, Wk, Wkb, n2, Wv, Wvb, n3, Wo, Wob, n4);

    const int Ntot = HDh + 2 * HkvDh;  // 3072
    gemm_t<0><<<dim3(Ntot / 64, M / 128), blk512, 0, stream>>>(
        hsb, Wqb, bq, bk, bv, qg16, kg16, vbuf, nullptr,
        M, Dm, S, Hkv, HDh, HkvDh, Ntot);

    const int nq = M * H;   // 32768 q row-heads
    ln_rope2<<<dim3((nq + M * Hkv) / 4), blk, 0, stream>>>(
        qg16, qbuf, kg16, kbuf, qg, qb_, kg, kb_, cosp, sinp, H, Hkv, S, nq);

    const float scale = 1.0f / sqrtf((float)Dh);
    attn<<<dim3(H * B, S / 64), blk, 0, stream>>>(qbuf, kbuf, vbuf, abuf, S, H, Hkv, nrep, scale);

    gemm_t<1><<<dim3(Dm / 64, M / 128), blk512, 0, stream>>>(
        abuf, Wob, bo, nullptr, nullptr, nullptr, nullptr, nullptr, (float*)d_out,
        M, HDh, S, Hkv, Dm, 0, Dm);
}

// Round 9
// 234.976 us; speedup vs baseline: 1.0619x; 1.0619x over previous
//
#include <hip/hip_runtime.h>
#include <cmath>

typedef __attribute__((ext_vector_type(8))) short bf16x8;
typedef __attribute__((ext_vector_type(4))) short s16x4;
typedef __attribute__((ext_vector_type(4))) float f32x4;

#define MFMA_BF16 __builtin_amdgcn_mfma_f32_16x16x32_bf16

__device__ __forceinline__ float bf2f(short s) {
    unsigned u = ((unsigned)(unsigned short)s) << 16;
    return __builtin_bit_cast(float, u);
}
__device__ __forceinline__ short f2bf(float f) {
    unsigned u = __builtin_bit_cast(unsigned, f);
    u += 0x7fffu + ((u >> 16) & 1u);   // RNE
    return (short)(u >> 16);
}

__device__ __forceinline__ void gl_lds16(const short* gp, short* lp) {
    __builtin_amdgcn_global_load_lds(
        (const __attribute__((address_space(1))) unsigned int*)gp,
        (__attribute__((address_space(3))) unsigned int*)lp, 16, 0, 0);
}

// Fused fp32->bf16 conversion for 5 tensors; every segment size is a
// multiple of 1024 so each 256-thread block (4 elems/thread) stays in one.
// (R4: fusing this into the GEMMs tripled FETCH_SIZE; dedup pass is load-
// bearing.)
__global__ __launch_bounds__(256) void cvt5(
    const float* s0, short* d0, int n0,
    const float* s1, short* d1, int n1,
    const float* s2, short* d2, int n2,
    const float* s3, short* d3, int n3,
    const float* s4, short* d4, int n4)
{
    long long i = (long long)blockIdx.x * 1024 + threadIdx.x * 4;
    const float* s; short* d;
    if      (i < n0)                  { s = s0; d = d0; }
    else if ((i -= n0) < n1)          { s = s1; d = d1; }
    else if ((i -= n1) < n2)          { s = s2; d = d2; }
    else if ((i -= n2) < n3)          { s = s3; d = d3; }
    else      { i -= n3;                s = s4; d = d4; }
    float4 v = *(const float4*)(s + i);
    s16x4 o;
    o[0] = f2bf(v.x); o[1] = f2bf(v.y); o[2] = f2bf(v.z); o[3] = f2bf(v.w);
    *(s16x4*)(d + i) = o;
}

// 128x64-tile GEMM (R5-proven 51.3us config): C = A @ W^T (+bias).
// 4 waves 2x2 (wave = 64x32, 4x2 accs), BK=64 double-buffered LDS (48 KB),
// global_load_lds staging, one __syncthreads per K-iter, 256 threads.
// STRUCTURE FROZEN — refuted levers: counted-vmcnt (R1), BK=32 (R3),
// cvt fusion (R4), 64x64 tile (R5), A-direct-to-reg (R6: barrier vmcnt(0)
// kills reg prefetch), 512-thread K-split (R8: +FETCH, +11us).
// XCD region swizzle (T1): each XCD owns a gx/4 x gy/2 region
// (FETCH 39->28.8 MB, -4.3us measured R5).
// LDS: per 32-K half, 1KB chunks of 16 rows; XOR swizzle f(row)=(row>>1)&3:
// lane L stages (row = chunk*16 + L>>2, kq = (L&3)^f(L>>2)) at slot L;
// fragment read slot = l15*4 + (quad^f(l15)) -> conflict-free b128; the
// in-row 64B permutation keeps global loads coalesced.
// MODE 0: QKV fused epilogue; MODE 1: fp32 out + bias (bq slot).
template <int MODE>
__global__ __launch_bounds__(256) void gemm_t(
    const short* __restrict__ A, const short* __restrict__ W,
    const float* __restrict__ bq, const float* __restrict__ bk,
    const float* __restrict__ bv,
    short* __restrict__ qo, short* __restrict__ ko, short* __restrict__ vo,
    float* __restrict__ fo,
    int M, int K, int S, int Hkv, int Nq, int Nkv, int N)
{
    __shared__ __align__(16) short As[2][2 * 8 * 512];   // 2 halves x 8 chunks
    __shared__ __align__(16) short Bs[2][2 * 4 * 512];   // 2 halves x 4 chunks

    const int w    = threadIdx.x >> 6;
    const int lane = threadIdx.x & 63;
    const int l15  = lane & 15;
    const int quad = lane >> 4;
    const int wy   = w >> 1;
    const int wx   = w & 1;

    // XCD region swizzle (bijective): xcd = lin&7 owns a gx/4 x gy/2 patch.
    unsigned gx = gridDim.x, gy = gridDim.y;
    unsigned bx = blockIdx.x, by = blockIdx.y;
    if ((gx & 3) == 0 && (gy & 1) == 0) {
        unsigned lin = by * gx + bx;
        unsigned xcd = lin & 7, idx = lin >> 3;
        unsigned n   = gx >> 2;
        bx = (xcd & 3) * n + idx % n;
        by = (xcd >> 2) * (gy >> 1) + idx / n;
    }
    const int m0 = by * 128;
    const int n0 = bx * 64;

    const short* Ab = A + (size_t)m0 * K;
    const short* Wb = W + (size_t)n0 * K;

    const int srow = lane >> 2;                              // 0..15
    const int scol = ((lane & 3) ^ ((srow >> 1) & 3)) * 8;   // swizzled col
    auto stage = [&](int buf, int kofs) {
#pragma unroll
        for (int h2 = 0; h2 < 2; h2++) {
#pragma unroll
            for (int i = 0; i < 2; i++) {
                const int c = 2 * w + i;
                gl_lds16(Ab + (size_t)(c * 16 + srow) * K + kofs + h2 * 32 + scol,
                         As[buf] + h2 * 4096 + c * 512 + lane * 8);
            }
            gl_lds16(Wb + (size_t)(w * 16 + srow) * K + kofs + h2 * 32 + scol,
                     Bs[buf] + h2 * 2048 + w * 512 + lane * 8);
        }
    };

    f32x4 acc[4][2];
#pragma unroll
    for (int i = 0; i < 4; i++)
#pragma unroll
        for (int j = 0; j < 2; j++) acc[i][j] = f32x4{0.f, 0.f, 0.f, 0.f};

    const int ridx = (l15 * 4 + (quad ^ ((l15 >> 1) & 3))) * 8;
    const int nk = K / 64;
    stage(0, 0);
    __syncthreads();

    for (int kt = 0; kt < nk; kt++) {
        const int cur = kt & 1;
        if (kt + 1 < nk) stage(cur ^ 1, (kt + 1) * 64);

#pragma unroll
        for (int h2 = 0; h2 < 2; h2++) {
            bf16x8 af[4], bfr[2];
#pragma unroll
            for (int i = 0; i < 4; i++)
                af[i] = *(const bf16x8*)(As[cur] + h2 * 4096 + (wy * 4 + i) * 512 + ridx);
#pragma unroll
            for (int j = 0; j < 2; j++)
                bfr[j] = *(const bf16x8*)(Bs[cur] + h2 * 2048 + (wx * 2 + j) * 512 + ridx);
#pragma unroll
            for (int i = 0; i < 4; i++)
#pragma unroll
                for (int j = 0; j < 2; j++)
                    acc[i][j] = MFMA_BF16(af[i], bfr[j], acc[i][j], 0, 0, 0);
        }
        __syncthreads();
    }

#pragma unroll
    for (int i = 0; i < 4; i++) {
#pragma unroll
        for (int j = 0; j < 2; j++) {
            const int col = n0 + wx * 32 + j * 16 + l15;
#pragma unroll
            for (int r = 0; r < 4; r++) {
                const int row = m0 + wy * 64 + i * 16 + quad * 4 + r;
                float v = acc[i][j][r];
                if constexpr (MODE == 0) {
                    if (col < Nq) {
                        qo[(size_t)row * Nq + col] = f2bf(v + bq[col]);
                    } else if (col < Nq + Nkv) {
                        int cn = col - Nq;
                        ko[(size_t)row * Nkv + cn] = f2bf(v + bk[cn]);
                    } else {
                        int cn = col - Nq - Nkv;
                        int b  = row / S, s = row - b * S;
                        int hk = cn >> 7, dh = cn & 127;   // Dh == 128
                        vo[(size_t)((b * Hkv + hk) * 128 + dh) * S + s] = f2bf(v + bv[cn]);
                    }
                } else {
                    fo[(size_t)row * N + col] = v + bq[col];
                }
            }
        }
    }
}

// Fused per-(token, head) LayerNorm (Dh=128) + RoPE. Launched K-only now
// (nq=0): Q's LN+RoPE is fused into attn's prologue (R9).
__global__ __launch_bounds__(256) void ln_rope2(
    const short* __restrict__ Xq, short* __restrict__ Yq,
    const short* __restrict__ Xk, short* __restrict__ Yk,
    const float* __restrict__ qg, const float* __restrict__ qbe,
    const float* __restrict__ kg, const float* __restrict__ kbe,
    const float* __restrict__ cosp, const float* __restrict__ sinp,
    int H, int Hkv, int S, int nq)
{
    int gw = blockIdx.x * 4 + (threadIdx.x >> 6);
    const int lane = threadIdx.x & 63;
    const short* X; short* Y; const float* g; const float* bt; int Hc;
    if (gw < nq) { X = Xq; Y = Yq; g = qg; bt = qbe; Hc = H; }
    else { gw -= nq; X = Xk; Y = Yk; g = kg; bt = kbe; Hc = Hkv; }

    const int h  = gw % Hc;
    const int rs = gw / Hc;          // b*S + s
    const int b  = rs / S;
    const int s  = rs - b * S;

    const short* x = X + ((size_t)rs * Hc + h) * 128;
    float x0 = bf2f(x[lane]), x1 = bf2f(x[lane + 64]);

    float sum = x0 + x1;
    float sq  = x0 * x0 + x1 * x1;
#pragma unroll
    for (int off = 32; off > 0; off >>= 1) {
        sum += __shfl_xor(sum, off, 64);
        sq  += __shfl_xor(sq, off, 64);
    }
    float mu  = sum * (1.f / 128.f);
    float var = sq * (1.f / 128.f) - mu * mu;
    float rinv = rsqrtf(var + 1e-5f);

    float y0 = (x0 - mu) * rinv * g[lane]      + bt[lane];
    float y1 = (x1 - mu) * rinv * g[lane + 64] + bt[lane + 64];

    float c0 = cosp[(size_t)s * 128 + lane];
    float c1 = cosp[(size_t)s * 128 + lane + 64];
    float s0 = sinp[(size_t)s * 128 + lane];
    float s1 = sinp[(size_t)s * 128 + lane + 64];

    float o0 = y0 * c0 - y1 * s0;
    float o1 = y1 * c1 + y0 * s1;

    short* yp = Y + ((size_t)(b * Hc + h) * S + s) * 128;
    yp[lane]      = f2bf(o0);
    yp[lane + 64] = f2bf(o1);
}

// Flash attention v3 (R5-proven loop, untouched) + R9: Q LayerNorm+RoPE
// fused into the prologue. Q is read RAW from the q-gemm output
// (row-major [M][H*128] bf16). Layout win: lane (l15,quad) holds row
// s=m0+l15, dims d = c*32+quad*8+e -- the full 128-dim row lives on the
// 4 quad-lanes {l15,+16,+32,+48}, so the LN reduce is exactly
// shfl_xor(16)+shfl_xor(32), and RoPE's d<->d+-64 partner is IN-LANE
// (qf[c] <-> qf[c^2]). One-time cost ~700cy/block vs deleting 80% of the
// ln_rope pass + the 16MB qbuf round-trip.
// Kt: (B,Hkv,S,128) LN+RoPE'd. Vt: (B,Hkv,128,S). O: (B,S,H*128).
__global__ __launch_bounds__(256, 2) void attn(
    const short* __restrict__ Qr, const short* __restrict__ Kt,
    const short* __restrict__ Vt, short* __restrict__ O,
    const float* __restrict__ qga, const float* __restrict__ qbe,
    const float* __restrict__ cosp, const float* __restrict__ sinp,
    int S, int H, int Hkv, int nrep, float scale)
{
    __shared__ __align__(16) short Ks[2][16 * 512];
    __shared__ __align__(16) short Vs[2][16 * 512];
    __shared__ __align__(16) short P[4][16][72];

    const int w    = threadIdx.x >> 6;
    const int lane = threadIdx.x & 63;
    const int l15  = lane & 15;
    const int quad = lane >> 4;
    const int bh   = blockIdx.x;
    const int h    = bh % H;
    const int b    = bh / H;
    const int nyt  = gridDim.y;
    const int y    = blockIdx.y;
    const int qblk = (y < (nyt >> 1)) ? (nyt - 1 - y) : (y - (nyt >> 1));
    const int hk   = h / nrep;
    const int m0   = qblk * 64 + w * 16;
    const int qpos = m0 + l15;

    const short* kb = Kt + (size_t)(b * Hkv + hk) * S * 128;
    const short* vb = Vt + (size_t)(b * Hkv + hk) * 128 * S;

    auto stage = [&](int buf, int j0) {
#pragma unroll
        for (int i = 0; i < 8; i++) {
            if (w < 2) {
                const int s = w * 8 + i;
                const int t = s >> 2, c = s & 3;
                gl_lds16(kb + (size_t)(j0 + t * 16 + l15) * 128 + c * 32 + quad * 8,
                         Ks[buf] + s * 512 + lane * 8);
            } else {
                const int u = (w - 2) * 8 + i;
                const int c = u >> 1, hf = u & 1;
                gl_lds16(vb + (size_t)(c * 16 + l15) * S + j0 + hf * 32 + quad * 8,
                         Vs[buf] + u * 512 + lane * 8);
            }
        }
    };

    // ---- fused Q LayerNorm + RoPE prologue ----
    const int HDh = H * 128;
    const short* qraw = Qr + (size_t)(b * S + qpos) * HDh + h * 128 + quad * 8;
    float yv[4][8];
    float sum = 0.f, sq = 0.f;
#pragma unroll
    for (int c = 0; c < 4; c++) {
        bf16x8 qv = *(const bf16x8*)(qraw + c * 32);
#pragma unroll
        for (int e = 0; e < 8; e++) {
            float x = bf2f(qv[e]);
            yv[c][e] = x; sum += x; sq += x * x;
        }
    }
    sum += __shfl_xor(sum, 16, 64); sum += __shfl_xor(sum, 32, 64);
    sq  += __shfl_xor(sq , 16, 64); sq  += __shfl_xor(sq , 32, 64);
    {
        float mu  = sum * (1.f / 128.f);
        float var = sq * (1.f / 128.f) - mu * mu;
        float rin = rsqrtf(var + 1e-5f);
#pragma unroll
        for (int c = 0; c < 4; c++) {
            const int d0 = c * 32 + quad * 8;
            float4 g0 = *(const float4*)(qga + d0);
            float4 g1 = *(const float4*)(qga + d0 + 4);
            float4 b0 = *(const float4*)(qbe + d0);
            float4 b1 = *(const float4*)(qbe + d0 + 4);
            float gg[8] = {g0.x,g0.y,g0.z,g0.w,g1.x,g1.y,g1.z,g1.w};
            float bb[8] = {b0.x,b0.y,b0.z,b0.w,b1.x,b1.y,b1.z,b1.w};
#pragma unroll
            for (int e = 0; e < 8; e++)
                yv[c][e] = (yv[c][e] - mu) * rin * gg[e] + bb[e];
        }
    }
    bf16x8 qf[4];
#pragma unroll
    for (int c = 0; c < 4; c++) {
        const int d0 = c * 32 + quad * 8;
        const float* cp = cosp + (size_t)qpos * 128 + d0;
        const float* sp = sinp + (size_t)qpos * 128 + d0;
        float4 c0v = *(const float4*)cp, c1v = *(const float4*)(cp + 4);
        float4 s0v = *(const float4*)sp, s1v = *(const float4*)(sp + 4);
        float cc[8] = {c0v.x,c0v.y,c0v.z,c0v.w,c1v.x,c1v.y,c1v.z,c1v.w};
        float ss[8] = {s0v.x,s0v.y,s0v.z,s0v.w,s1v.x,s1v.y,s1v.z,s1v.w};
        const float sgn = (c < 2) ? -1.f : 1.f;
#pragma unroll
        for (int e = 0; e < 8; e++) {
            float o = yv[c][e] * cc[e] + sgn * yv[c ^ 2][e] * ss[e];
            qf[c][e] = f2bf(o);
        }
    }
    // ---- end prologue ----

    f32x4 of[8];
#pragma unroll
    for (int c = 0; c < 8; c++) of[c] = f32x4{0.f, 0.f, 0.f, 0.f};
    float m_s = -1e30f, l_s = 0.f;
    const float c2 = scale * 1.44269504f;

    const int nkt = qblk + 1;
    stage(0, 0);
    __syncthreads();

    for (int kt = 0; kt < nkt; kt++) {
        const int cur = kt & 1;
        if (kt + 1 < nkt) stage(cur ^ 1, (kt + 1) * 64);

        const short* Kb = Ks[cur];
        const short* Vb = Vs[cur];
        const int j0 = kt * 64;

        f32x4 sc[4];
#pragma unroll
        for (int t = 0; t < 4; t++) sc[t] = f32x4{0.f, 0.f, 0.f, 0.f};
#pragma unroll
        for (int c = 0; c < 4; c++)
#pragma unroll
            for (int t = 0; t < 4; t++) {
                bf16x8 kf = *(const bf16x8*)(Kb + (t * 4 + c) * 512 + lane * 8);
                sc[t] = MFMA_BF16(kf, qf[c], sc[t], 0, 0, 0);
            }

        float v[4][4];
        float mx = -1e30f;
#pragma unroll
        for (int t = 0; t < 4; t++)
#pragma unroll
            for (int r = 0; r < 4; r++) {
                float s_ = sc[t][r];
                if (j0 + t * 16 + quad * 4 + r > qpos) s_ = -1e30f;
                v[t][r] = s_;
                mx = fmaxf(mx, s_);
            }
        mx = fmaxf(mx, __shfl_xor(mx, 16, 64));
        mx = fmaxf(mx, __shfl_xor(mx, 32, 64));
        float mnew  = fmaxf(m_s, mx);
        float mc    = mnew * c2;
        float alpha = exp2f(m_s * c2 - mc);
        float sum2 = 0.f;
        float p[4][4];
#pragma unroll
        for (int t = 0; t < 4; t++)
#pragma unroll
            for (int r = 0; r < 4; r++) {
                p[t][r] = exp2f(__builtin_fmaf(v[t][r], c2, -mc));
                sum2 += p[t][r];
            }
        sum2 += __shfl_xor(sum2, 16, 64);
        sum2 += __shfl_xor(sum2, 32, 64);
        l_s = l_s * alpha + sum2;
        m_s = mnew;

#pragma unroll
        for (int c = 0; c < 8; c++) {
            f32x4 t = of[c];
            t[0] *= alpha; t[1] *= alpha; t[2] *= alpha; t[3] *= alpha;
            of[c] = t;
        }

#pragma unroll
        for (int t = 0; t < 4; t++) {
            s16x4 pk;
#pragma unroll
            for (int r = 0; r < 4; r++) pk[r] = f2bf(p[t][r]);
            *(s16x4*)(&P[w][l15][t * 16 + quad * 4]) = pk;
        }
        bf16x8 pb0 = *(const bf16x8*)(&P[w][l15][quad * 8]);
        bf16x8 pb1 = *(const bf16x8*)(&P[w][l15][32 + quad * 8]);

#pragma unroll
        for (int c = 0; c < 8; c++) {
            bf16x8 vf0 = *(const bf16x8*)(Vb + (c * 2 + 0) * 512 + lane * 8);
            bf16x8 vf1 = *(const bf16x8*)(Vb + (c * 2 + 1) * 512 + lane * 8);
            of[c] = MFMA_BF16(vf0, pb0, of[c], 0, 0, 0);
            of[c] = MFMA_BF16(vf1, pb1, of[c], 0, 0, 0);
        }
        __syncthreads();
    }

    const float rinv = 1.0f / l_s;
    short* orow = O + ((size_t)b * S + qpos) * HDh + h * 128;
#pragma unroll
    for (int c = 0; c < 8; c++) {
        s16x4 ov;
#pragma unroll
        for (int r = 0; r < 4; r++) ov[r] = f2bf(of[c][r] * rinv);
        *(s16x4*)(orow + c * 16 + quad * 4) = ov;
    }
}

extern "C" void kernel_launch(void* const* d_in, const int* in_sizes, int n_in,
                              void* d_out, int out_size, void* d_ws, size_t ws_size,
                              hipStream_t stream) {
    const float* hs   = (const float*)d_in[0];
    const float* cosp = (const float*)d_in[1];
    const float* sinp = (const float*)d_in[2];
    const float* Wq   = (const float*)d_in[3];
    const float* bq   = (const float*)d_in[4];
    const float* Wk   = (const float*)d_in[5];
    const float* bk   = (const float*)d_in[6];
    const float* Wv   = (const float*)d_in[7];
    const float* bv   = (const float*)d_in[8];
    const float* Wo   = (const float*)d_in[9];
    const float* bo   = (const float*)d_in[10];
    const float* qg   = (const float*)d_in[11];
    const float* qb_  = (const float*)d_in[12];
    const float* kg   = (const float*)d_in[13];
    const float* kb_  = (const float*)d_in[14];

    const int Dh    = in_sizes[11];          // 128
    const int Dm    = in_sizes[10];          // 2048
    const int HDh   = in_sizes[4];           // 2048
    const int H     = HDh / Dh;              // 16
    const int HkvDh = in_sizes[6];           // 512
    const int Hkv   = HkvDh / Dh;            // 4
    const int S     = in_sizes[1] / Dh;      // 1024
    const int B     = in_sizes[0] / (S * Dm);// 2
    const int M     = B * S;                 // 2048
    const int nrep  = H / Hkv;               // 4

    // workspace layout; Wqb/Wkb/Wvb contiguous => packed (HDh+2*HkvDh, Dm)
    char* ws = (char*)d_ws;
    short* hsb  = (short*)ws;  ws += (size_t)M * Dm      * 2;  // 8 MB
    short* Wqb  = (short*)ws;  ws += (size_t)HDh * Dm    * 2;  // 8 MB
    short* Wkb  = (short*)ws;  ws += (size_t)HkvDh * Dm  * 2;  // 2 MB
    short* Wvb  = (short*)ws;  ws += (size_t)HkvDh * Dm  * 2;  // 2 MB
    short* Wob  = (short*)ws;  ws += (size_t)Dm * HDh    * 2;  // 8 MB
    short* qg16 = (short*)ws;  ws += (size_t)M * HDh     * 2;  // 8 MB (raw Q, read by attn)
    short* kg16 = (short*)ws;  ws += (size_t)M * HkvDh   * 2;  // 2 MB
    short* abuf = (short*)ws;  ws += (size_t)M * HDh     * 2;  // 8 MB (attn out)
    short* kbuf = (short*)ws;  ws += (size_t)M * HkvDh   * 2;  // 2 MB
    short* vbuf = (short*)ws;  ws += (size_t)M * HkvDh   * 2;  // 2 MB

    dim3 blk(256);
    const int n0 = M * Dm, n1 = HDh * Dm, n2 = HkvDh * Dm, n3 = HkvDh * Dm, n4 = Dm * HDh;
    cvt5<<<dim3((n0 + n1 + n2 + n3 + n4) / 1024), blk, 0, stream>>>(
        hs, hsb, n0, Wq, Wqb, n1, Wk, Wkb, n2, Wv, Wvb, n3, Wo, Wob, n4);

    const int Ntot = HDh + 2 * HkvDh;  // 3072
    gemm_t<0><<<dim3(Ntot / 64, M / 128), blk, 0, stream>>>(
        hsb, Wqb, bq, bk, bv, qg16, kg16, vbuf, nullptr,
        M, Dm, S, Hkv, HDh, HkvDh, Ntot);

    // K-only LN+RoPE (Q fused into attn): M*Hkv = 8192 row-heads.
    ln_rope2<<<dim3((M * Hkv) / 4), blk, 0, stream>>>(
        kg16, kbuf, kg16, kbuf, kg, kb_, kg, kb_, cosp, sinp, Hkv, Hkv, S, 0);

    const float scale = 1.0f / sqrtf((float)Dh);
    attn<<<dim3(H * B, S / 64), blk, 0, stream>>>(
        qg16, kbuf, vbuf, abuf, qg, qb_, cosp, sinp, S, H, Hkv, nrep, scale);

    gemm_t<1><<<dim3(Dm / 64, M / 128), blk, 0, stream>>>(
        abuf, Wob, bo, nullptr, nullptr, nullptr, nullptr, nullptr, (float*)d_out,
        M, HDh, S, Hkv, Dm, 0, Dm);
}